// Round 4
// baseline (297.963 us; speedup 1.0000x reference)
//
#include <hip/hip_runtime.h>

#define N_NODES 100000
#define N_EDGES 600000
#define NT2 9375    // edge tiles of 64 (600000 = 9375*64 exactly)
#define LDW 264     // raw-tile row stride (f16): 256 data cols + 8 pad
#define LDH 136     // h1-tile row stride (f16): 128 data cols + 8 pad
typedef _Float16 f16x8 __attribute__((ext_vector_type(8)));
typedef __attribute__((ext_vector_type(4))) float f32x4;

__device__ __forceinline__ float elu_f(float v) {
    return v > 0.0f ? v : (__expf(v) - 1.0f);
}

// k0: x f32 -> f16 gather table. Pure streaming, ~77MB total traffic.
extern "C" __global__ __launch_bounds__(256)
void k0_convert(const float* __restrict__ x, _Float16* __restrict__ xh) {
    const int step = gridDim.x * blockDim.x;
    for (int c = blockIdx.x * blockDim.x + threadIdx.x; c < (N_NODES * 128) / 8;
         c += step) {
        const float4 a0 = *(const float4*)(x + (size_t)c * 8);
        const float4 a1 = *(const float4*)(x + (size_t)c * 8 + 4);
        f16x8 h;
        h[0] = (_Float16)a0.x; h[1] = (_Float16)a0.y;
        h[2] = (_Float16)a0.z; h[3] = (_Float16)a0.w;
        h[4] = (_Float16)a1.x; h[5] = (_Float16)a1.y;
        h[6] = (_Float16)a1.z; h[7] = (_Float16)a1.w;
        *(f16x8*)(xh + (size_t)c * 8) = h;
    }
}

// k2 fused, v2 schedule. R3's fused dataflow was right but the schedule lost
// the 85us kernel's execution shape: 70KB LDS -> 2 blocks/CU and 3 barriers.
// Fix: single-buffer the raw tile (gathered rows live in regs until the
// barrier anyway) -> 52.2KB LDS -> 3 blocks/CU, grid 768, 2 barriers/tile.
//   per tile: [gather nt -> regs | layer-1 MFMA on sRaw] B1
//             [out-write prev | h1 -> sH1 | regs -> sRaw] B2
//             [layer-2 MFMA on sH1 + reduce -> sPart]
extern "C" __global__ __launch_bounds__(256, 3)
void k2_edge_mlp(const _Float16* __restrict__ xh, const void* __restrict__ eiv,
                 const float* __restrict__ W1, const float* __restrict__ b1,
                 const float* __restrict__ W2, const float* __restrict__ b2,
                 const float* __restrict__ W3, const float* __restrict__ b3,
                 float* __restrict__ out) {
    __shared__ __align__(16) _Float16 sRaw[64 * LDW];  // 33.8 KB
    __shared__ __align__(16) _Float16 sH1[64 * LDH];   // 17.4 KB
    __shared__ float sPart[4][64];                     // 1 KB
    __shared__ int sFlag;

    const int t = threadIdx.x;
    const int w = t >> 6, lane = t & 63;
    const int ln = lane & 15, kg = lane >> 4;
    const int row_s = t >> 2;        // staging row 0..63
    const int qb = (t & 3) * 32;     // staging 32-col chunk base
    const float b3v = b3[0];
    const int stride = gridDim.x;

    if (t < 64) {
        unsigned v = ((const unsigned*)eiv)[2 * t + 1];
        unsigned long long bm = __ballot(v == 0u);
        if (t == 0) sFlag = (bm == ~0ull) ? 1 : 0;
    }

    // Layer-1 B-frags: both W1 k-halves, this wave's 32-col strip. 64 VGPR.
    f16x8 bf1[2][2][4];
#pragma unroll
    for (int half = 0; half < 2; ++half)
#pragma unroll
        for (int c = 0; c < 2; ++c) {
            const int n = w * 32 + c * 16 + ln;
#pragma unroll
            for (int ks = 0; ks < 4; ++ks) {
                f16x8 v;
#pragma unroll
                for (int j = 0; j < 8; ++j) {
                    int k = half * 128 + ks * 32 + kg * 8 + j;
                    v[j] = (_Float16)W1[k * 128 + n];
                }
                bf1[half][c][ks] = v;
            }
        }

    // Layer-2 B-frags. 32 VGPR.
    f16x8 bf2[2][4];
#pragma unroll
    for (int c = 0; c < 2; ++c) {
        const int n = w * 32 + c * 16 + ln;
#pragma unroll
        for (int ks = 0; ks < 4; ++ks) {
            f16x8 v;
#pragma unroll
            for (int j = 0; j < 8; ++j) {
                int k = ks * 32 + kg * 8 + j;
                v[j] = (_Float16)W2[k * 128 + n];
            }
            bf2[c][ks] = v;
        }
    }

    float b1v[2], b2v[2], w3v[2];
#pragma unroll
    for (int c = 0; c < 2; ++c) {
        int col = w * 32 + c * 16 + ln;
        b1v[c] = b1[col]; b2v[c] = b2[col]; w3v[c] = W3[col];
    }

    __syncthreads();
    const int mode64 = sFlag;
    const int tile0 = blockIdx.x;   // 768 <= NT2 always

    int se_nx, ge_nx;
    // Prologue: stage tile0 into sRaw.
    {
        int e = tile0 * 64 + row_s;
        int se, ge;
        if (mode64) {
            se = (int)((const long long*)eiv)[e];
            ge = (int)((const long long*)eiv)[N_EDGES + e];
        } else {
            se = ((const int*)eiv)[e];
            ge = ((const int*)eiv)[N_EDGES + e];
        }
        const _Float16* pa = xh + (size_t)se * 128 + qb;
        const _Float16* pb = xh + (size_t)ge * 128 + qb;
#pragma unroll
        for (int i = 0; i < 4; ++i) {
            f16x8 ga = *(const f16x8*)(pa + i * 8);
            f16x8 gb = *(const f16x8*)(pb + i * 8);
            *(f16x8*)(&sRaw[row_s * LDW + qb + i * 8]) = ga;
            *(f16x8*)(&sRaw[row_s * LDW + 128 + qb + i * 8]) = gb;
        }
    }
    {
        int t1 = tile0 + stride;
        int t1c = (t1 < NT2) ? t1 : tile0;
        int e = t1c * 64 + row_s;
        if (mode64) {
            se_nx = (int)((const long long*)eiv)[e];
            ge_nx = (int)((const long long*)eiv)[N_EDGES + e];
        } else {
            se_nx = ((const int*)eiv)[e];
            ge_nx = ((const int*)eiv)[N_EDGES + e];
        }
    }
    __syncthreads();   // sRaw ready

    int prevE0 = -1;
    for (int tile = tile0; tile < NT2; tile += stride) {
        const int nt = tile + stride;
        const int ntc = (nt < NT2) ? nt : tile;

        // (1) Issue gathers for tile nt; held in regs across layer-1.
        const _Float16* pa = xh + (size_t)se_nx * 128 + qb;
        const _Float16* pb = xh + (size_t)ge_nx * 128 + qb;
        f16x8 Ga[4], Gb[4];
#pragma unroll
        for (int i = 0; i < 4; ++i) {
            Ga[i] = *(const f16x8*)(pa + i * 8);
            Gb[i] = *(const f16x8*)(pb + i * 8);
        }

        // (1b) Indices for tile nt+stride.
        {
            int n2 = nt + stride;
            int n2c = (n2 < NT2) ? n2 : ntc;
            int e = n2c * 64 + row_s;
            if (mode64) {
                se_nx = (int)((const long long*)eiv)[e];
                ge_nx = (int)((const long long*)eiv)[N_EDGES + e];
            } else {
                se_nx = ((const int*)eiv)[e];
                ge_nx = ((const int*)eiv)[N_EDGES + e];
            }
        }

        // (2) Layer 1: h1 = src.W1a + tgt.W1b, f32 accumulate, from sRaw.
        f32x4 acc1[4][2];
#pragma unroll
        for (int rt = 0; rt < 4; ++rt)
#pragma unroll
            for (int c = 0; c < 2; ++c) acc1[rt][c] = (f32x4){0.f, 0.f, 0.f, 0.f};

#pragma unroll
        for (int ks = 0; ks < 4; ++ks) {
#pragma unroll
            for (int rt = 0; rt < 4; ++rt) {
                f16x8 a_s = *(const f16x8*)(&sRaw[(rt * 16 + ln) * LDW + ks * 32 + kg * 8]);
                f16x8 a_t = *(const f16x8*)(&sRaw[(rt * 16 + ln) * LDW + 128 + ks * 32 + kg * 8]);
#pragma unroll
                for (int c = 0; c < 2; ++c) {
                    acc1[rt][c] = __builtin_amdgcn_mfma_f32_16x16x32_f16(
                        a_s, bf1[0][c][ks], acc1[rt][c], 0, 0, 0);
                    acc1[rt][c] = __builtin_amdgcn_mfma_f32_16x16x32_f16(
                        a_t, bf1[1][c][ks], acc1[rt][c], 0, 0, 0);
                }
            }
        }
        __syncthreads();   // B1: layer-1 reads of sRaw done; sPart(prev) ready

        // (3a) Out-write for the previous tile (overlaps LDS writes below).
        if (prevE0 >= 0 && t < 64)
            out[prevE0 + t] = sPart[0][t] + sPart[1][t] +
                              sPart[2][t] + sPart[3][t] + b3v;

        // (3b) elu -> h1 (f16) into sH1 (C-layout [m89/m91]).
#pragma unroll
        for (int rt = 0; rt < 4; ++rt)
#pragma unroll
            for (int c = 0; c < 2; ++c) {
                const int col = w * 32 + c * 16 + ln;
#pragma unroll
                for (int reg = 0; reg < 4; ++reg) {
                    const int row = rt * 16 + kg * 4 + reg;
                    sH1[row * LDH + col] =
                        (_Float16)elu_f(acc1[rt][c][reg] + b1v[c]);
                }
            }

        // (3c) Stage gathered tile nt -> sRaw (reads done at B1).
#pragma unroll
        for (int i = 0; i < 4; ++i) {
            *(f16x8*)(&sRaw[row_s * LDW + qb + i * 8]) = Ga[i];
            *(f16x8*)(&sRaw[row_s * LDW + 128 + qb + i * 8]) = Gb[i];
        }
        __syncthreads();   // B2: sH1 + sRaw(next) ready

        // (4) Layer 2 + fused layer 3 reduce -> sPart.
        f32x4 acc2[4][2];
#pragma unroll
        for (int rt = 0; rt < 4; ++rt)
#pragma unroll
            for (int c = 0; c < 2; ++c) acc2[rt][c] = (f32x4){0.f, 0.f, 0.f, 0.f};

#pragma unroll
        for (int ks = 0; ks < 4; ++ks) {
#pragma unroll
            for (int rt = 0; rt < 4; ++rt) {
                f16x8 a = *(const f16x8*)(&sH1[(rt * 16 + ln) * LDH + ks * 32 + kg * 8]);
#pragma unroll
                for (int c = 0; c < 2; ++c)
                    acc2[rt][c] = __builtin_amdgcn_mfma_f32_16x16x32_f16(
                        a, bf2[c][ks], acc2[rt][c], 0, 0, 0);
            }
        }

#pragma unroll
        for (int rt = 0; rt < 4; ++rt) {
            float pr[4] = {0.f, 0.f, 0.f, 0.f};
#pragma unroll
            for (int c = 0; c < 2; ++c) {
#pragma unroll
                for (int reg = 0; reg < 4; ++reg)
                    pr[reg] += elu_f(acc2[rt][c][reg] + b2v[c]) * w3v[c];
            }
#pragma unroll
            for (int m = 1; m < 16; m <<= 1)
#pragma unroll
                for (int reg = 0; reg < 4; ++reg) pr[reg] += __shfl_xor(pr[reg], m, 64);
            if (ln == 0) {
#pragma unroll
                for (int reg = 0; reg < 4; ++reg)
                    sPart[w][rt * 16 + kg * 4 + reg] = pr[reg];
            }
        }
        // No barrier here: next iter's B1 orders sPart writes vs out-read,
        // and layer-1 only READS sRaw (written before B2).

        prevE0 = tile * 64;
    }

    __syncthreads();   // final sPart ready
    if (prevE0 >= 0 && t < 64)
        out[prevE0 + t] = sPart[0][t] + sPart[1][t] +
                          sPart[2][t] + sPart[3][t] + b3v;
}

extern "C" void kernel_launch(void* const* d_in, const int* in_sizes, int n_in,
                              void* d_out, int out_size, void* d_ws, size_t ws_size,
                              hipStream_t stream) {
    const float* x  = (const float*)d_in[0];
    const void*  ei = d_in[1];
    const float* W1 = (const float*)d_in[2];
    const float* b1 = (const float*)d_in[3];
    const float* W2 = (const float*)d_in[4];
    const float* b2 = (const float*)d_in[5];
    const float* W3 = (const float*)d_in[6];
    const float* b3 = (const float*)d_in[7];
    float* out = (float*)d_out;

    _Float16* xh = (_Float16*)((char*)d_ws + 256);  // 100000*128 f16 = 25.6 MB

    k0_convert<<<2048, 256, 0, stream>>>(x, xh);
    k2_edge_mlp<<<768, 256, 0, stream>>>(xh, ei, W1, b1, W2, b2, W3, b3, out);
}

// Round 5
// 205.879 us; speedup vs baseline: 1.4473x; 1.4473x over previous
//
#include <hip/hip_runtime.h>

#define N_NODES 100000
#define N_EDGES 600000
#define NT2 9375    // edge tiles of 64 (600000 = 9375*64 exactly)
#define LDW 264     // raw-tile row stride (f16): 256 data cols + 8 pad
#define LDH 136     // h1-tile row stride (f16): 128 data cols + 8 pad
typedef _Float16 f16x8 __attribute__((ext_vector_type(8)));
typedef __attribute__((ext_vector_type(4))) float f32x4;

__device__ __forceinline__ float elu_f(float v) {
    return v > 0.0f ? v : (__expf(v) - 1.0f);
}

// k0: (a) x f32 -> f16 gather table (streaming, ~77MB); (b) first 16 blocks
// also build W1f: W1 pre-swizzled into MFMA-fragment order so k2 can stream
// W1 frags with ONE coalesced dwordx4 per frag instead of holding 64 VGPR
// resident. Entry id = (w*16 + half*8 + c*4 + ks)*64 + lane; 4096 x 16B = 64KB.
extern "C" __global__ __launch_bounds__(256)
void k0_convert(const float* __restrict__ x, const float* __restrict__ W1,
                _Float16* __restrict__ xh, _Float16* __restrict__ W1f) {
    const int t = threadIdx.x;
    if (blockIdx.x < 16) {
        const int id = blockIdx.x * 256 + t;   // 0..4095
        const int lane = id & 63, f = id >> 6;
        const int ks = f & 3, c = (f >> 2) & 1, half = (f >> 3) & 1, w = f >> 4;
        const int ln = lane & 15, kg = lane >> 4;
        const int col = w * 32 + c * 16 + ln;
        f16x8 v;
#pragma unroll
        for (int j = 0; j < 8; ++j)
            v[j] = (_Float16)W1[(half * 128 + ks * 32 + kg * 8 + j) * 128 + col];
        *(f16x8*)(W1f + (size_t)id * 8) = v;
    }
    const int step = gridDim.x * blockDim.x;
    for (int c = blockIdx.x * blockDim.x + t; c < (N_NODES * 128) / 8; c += step) {
        const float4 a0 = *(const float4*)(x + (size_t)c * 8);
        const float4 a1 = *(const float4*)(x + (size_t)c * 8 + 4);
        f16x8 h;
        h[0] = (_Float16)a0.x; h[1] = (_Float16)a0.y;
        h[2] = (_Float16)a0.z; h[3] = (_Float16)a0.w;
        h[4] = (_Float16)a1.x; h[5] = (_Float16)a1.y;
        h[6] = (_Float16)a1.z; h[7] = (_Float16)a1.w;
        *(f16x8*)(xh + (size_t)c * 8) = h;
    }
}

// k2 fused, v3: fix round-4's scratch-spill catastrophe (WRITE 293MB, FETCH
// 385MB = spill/refill traffic). Cause: (256,3) caps VGPR at 128 (HW occupancy
// steps at 64/128/256 [m69]) but full W1+W2 residency needs ~150. Fix: W1
// frags are tile-INVARIANT -> stream them from L2-hot W1f (4 coalesced 16B
// loads per ks, 16 transient VGPR) instead of 64 resident. Peak live set
// ~122 <= 128 -> no spill, 3 blocks/CU, grid 768, 2 barriers/tile.
extern "C" __global__ __launch_bounds__(256, 3)
void k2_edge_mlp(const _Float16* __restrict__ xh, const void* __restrict__ eiv,
                 const _Float16* __restrict__ W1f, const float* __restrict__ b1,
                 const float* __restrict__ W2, const float* __restrict__ b2,
                 const float* __restrict__ W3, const float* __restrict__ b3,
                 float* __restrict__ out) {
    __shared__ __align__(16) _Float16 sRaw[64 * LDW];  // 33.8 KB
    __shared__ __align__(16) _Float16 sH1[64 * LDH];   // 17.4 KB
    __shared__ float sPart[4][64];                     // 1 KB
    __shared__ int sFlag;

    const int t = threadIdx.x;
    const int w = t >> 6, lane = t & 63;
    const int ln = lane & 15, kg = lane >> 4;
    const int row_s = t >> 2;        // staging row 0..63
    const int qb = (t & 3) * 32;     // staging 32-col chunk base
    const float b3v = b3[0];
    const int stride = gridDim.x;

    if (t < 64) {
        unsigned v = ((const unsigned*)eiv)[2 * t + 1];
        unsigned long long bm = __ballot(v == 0u);
        if (t == 0) sFlag = (bm == ~0ull) ? 1 : 0;
    }

    // This wave's W1f slice base (16 frags of 512 f16 each).
    const _Float16* w1w = W1f + (size_t)(w * 16) * 512;

    // Layer-2 B-frags: resident, 32 VGPR.
    f16x8 bf2[2][4];
#pragma unroll
    for (int c = 0; c < 2; ++c) {
        const int n = w * 32 + c * 16 + ln;
#pragma unroll
        for (int ks = 0; ks < 4; ++ks) {
            f16x8 v;
#pragma unroll
            for (int j = 0; j < 8; ++j) {
                int k = ks * 32 + kg * 8 + j;
                v[j] = (_Float16)W2[k * 128 + n];
            }
            bf2[c][ks] = v;
        }
    }

    float b1v[2], b2v[2], w3v[2];
#pragma unroll
    for (int c = 0; c < 2; ++c) {
        int col = w * 32 + c * 16 + ln;
        b1v[c] = b1[col]; b2v[c] = b2[col]; w3v[c] = W3[col];
    }

    __syncthreads();
    const int mode64 = sFlag;
    const int tile0 = blockIdx.x;   // 768 <= NT2 always

    int se_nx, ge_nx;
    // Prologue: stage tile0 into sRaw.
    {
        int e = tile0 * 64 + row_s;
        int se, ge;
        if (mode64) {
            se = (int)((const long long*)eiv)[e];
            ge = (int)((const long long*)eiv)[N_EDGES + e];
        } else {
            se = ((const int*)eiv)[e];
            ge = ((const int*)eiv)[N_EDGES + e];
        }
        const _Float16* pa = xh + (size_t)se * 128 + qb;
        const _Float16* pb = xh + (size_t)ge * 128 + qb;
#pragma unroll
        for (int i = 0; i < 4; ++i) {
            f16x8 ga = *(const f16x8*)(pa + i * 8);
            f16x8 gb = *(const f16x8*)(pb + i * 8);
            *(f16x8*)(&sRaw[row_s * LDW + qb + i * 8]) = ga;
            *(f16x8*)(&sRaw[row_s * LDW + 128 + qb + i * 8]) = gb;
        }
    }
    {
        int t1 = tile0 + stride;
        int t1c = (t1 < NT2) ? t1 : tile0;
        int e = t1c * 64 + row_s;
        if (mode64) {
            se_nx = (int)((const long long*)eiv)[e];
            ge_nx = (int)((const long long*)eiv)[N_EDGES + e];
        } else {
            se_nx = ((const int*)eiv)[e];
            ge_nx = ((const int*)eiv)[N_EDGES + e];
        }
    }
    __syncthreads();   // sRaw ready

    int prevE0 = -1;
    for (int tile = tile0; tile < NT2; tile += stride) {
        const int nt = tile + stride;
        const int ntc = (nt < NT2) ? nt : tile;

        // (1) Issue gathers for tile nt; held in regs across layer-1.
        const _Float16* pa = xh + (size_t)se_nx * 128 + qb;
        const _Float16* pb = xh + (size_t)ge_nx * 128 + qb;
        f16x8 Ga[4], Gb[4];
#pragma unroll
        for (int i = 0; i < 4; ++i) {
            Ga[i] = *(const f16x8*)(pa + i * 8);
            Gb[i] = *(const f16x8*)(pb + i * 8);
        }

        // (1b) Indices for tile nt+stride.
        {
            int n2 = nt + stride;
            int n2c = (n2 < NT2) ? n2 : ntc;
            int e = n2c * 64 + row_s;
            if (mode64) {
                se_nx = (int)((const long long*)eiv)[e];
                ge_nx = (int)((const long long*)eiv)[N_EDGES + e];
            } else {
                se_nx = ((const int*)eiv)[e];
                ge_nx = ((const int*)eiv)[N_EDGES + e];
            }
        }

        // (2) Layer 1: h1 = src.W1a + tgt.W1b. W1 frags STREAMED per ks
        //     (unroll 1 keeps only 4 frags = 16 VGPR live; L2-hot).
        f32x4 acc1[4][2];
#pragma unroll
        for (int rt = 0; rt < 4; ++rt)
#pragma unroll
            for (int c = 0; c < 2; ++c) acc1[rt][c] = (f32x4){0.f, 0.f, 0.f, 0.f};

#pragma unroll 1
        for (int ks = 0; ks < 4; ++ks) {
            f16x8 w1f[2][2];
#pragma unroll
            for (int half = 0; half < 2; ++half)
#pragma unroll
                for (int c = 0; c < 2; ++c)
                    w1f[half][c] = *(const f16x8*)(
                        w1w + ((half * 8 + c * 4 + ks) * 64 + lane) * 8);
#pragma unroll
            for (int rt = 0; rt < 4; ++rt) {
                f16x8 a_s = *(const f16x8*)(&sRaw[(rt * 16 + ln) * LDW + ks * 32 + kg * 8]);
                f16x8 a_t = *(const f16x8*)(&sRaw[(rt * 16 + ln) * LDW + 128 + ks * 32 + kg * 8]);
#pragma unroll
                for (int c = 0; c < 2; ++c) {
                    acc1[rt][c] = __builtin_amdgcn_mfma_f32_16x16x32_f16(
                        a_s, w1f[0][c], acc1[rt][c], 0, 0, 0);
                    acc1[rt][c] = __builtin_amdgcn_mfma_f32_16x16x32_f16(
                        a_t, w1f[1][c], acc1[rt][c], 0, 0, 0);
                }
            }
        }
        __syncthreads();   // B1: layer-1 reads of sRaw done; sPart(prev) ready

        // (3a) Out-write for the previous tile (overlaps LDS writes below).
        if (prevE0 >= 0 && t < 64)
            out[prevE0 + t] = sPart[0][t] + sPart[1][t] +
                              sPart[2][t] + sPart[3][t] + b3v;

        // (3b) elu -> h1 (f16) into sH1 (C-layout [m89/m91]).
#pragma unroll
        for (int rt = 0; rt < 4; ++rt)
#pragma unroll
            for (int c = 0; c < 2; ++c) {
                const int col = w * 32 + c * 16 + ln;
#pragma unroll
                for (int reg = 0; reg < 4; ++reg) {
                    const int row = rt * 16 + kg * 4 + reg;
                    sH1[row * LDH + col] =
                        (_Float16)elu_f(acc1[rt][c][reg] + b1v[c]);
                }
            }

        // (3c) Stage gathered tile nt -> sRaw (reads done at B1).
#pragma unroll
        for (int i = 0; i < 4; ++i) {
            *(f16x8*)(&sRaw[row_s * LDW + qb + i * 8]) = Ga[i];
            *(f16x8*)(&sRaw[row_s * LDW + 128 + qb + i * 8]) = Gb[i];
        }
        __syncthreads();   // B2: sH1 + sRaw(next) ready

        // (4) Layer 2 + fused layer 3 reduce -> sPart.
        f32x4 acc2[4][2];
#pragma unroll
        for (int rt = 0; rt < 4; ++rt)
#pragma unroll
            for (int c = 0; c < 2; ++c) acc2[rt][c] = (f32x4){0.f, 0.f, 0.f, 0.f};

#pragma unroll
        for (int ks = 0; ks < 4; ++ks) {
#pragma unroll
            for (int rt = 0; rt < 4; ++rt) {
                f16x8 a = *(const f16x8*)(&sH1[(rt * 16 + ln) * LDH + ks * 32 + kg * 8]);
#pragma unroll
                for (int c = 0; c < 2; ++c)
                    acc2[rt][c] = __builtin_amdgcn_mfma_f32_16x16x32_f16(
                        a, bf2[c][ks], acc2[rt][c], 0, 0, 0);
            }
        }

#pragma unroll
        for (int rt = 0; rt < 4; ++rt) {
            float pr[4] = {0.f, 0.f, 0.f, 0.f};
#pragma unroll
            for (int c = 0; c < 2; ++c) {
#pragma unroll
                for (int reg = 0; reg < 4; ++reg)
                    pr[reg] += elu_f(acc2[rt][c][reg] + b2v[c]) * w3v[c];
            }
#pragma unroll
            for (int m = 1; m < 16; m <<= 1)
#pragma unroll
                for (int reg = 0; reg < 4; ++reg) pr[reg] += __shfl_xor(pr[reg], m, 64);
            if (ln == 0) {
#pragma unroll
                for (int reg = 0; reg < 4; ++reg)
                    sPart[w][rt * 16 + kg * 4 + reg] = pr[reg];
            }
        }
        // No barrier: next iter's B1 orders sPart writes vs out-read, and
        // layer-1 only READS sRaw (fully written before B2).

        prevE0 = tile * 64;
    }

    __syncthreads();   // final sPart ready
    if (prevE0 >= 0 && t < 64)
        out[prevE0 + t] = sPart[0][t] + sPart[1][t] +
                          sPart[2][t] + sPart[3][t] + b3v;
}

extern "C" void kernel_launch(void* const* d_in, const int* in_sizes, int n_in,
                              void* d_out, int out_size, void* d_ws, size_t ws_size,
                              hipStream_t stream) {
    const float* x  = (const float*)d_in[0];
    const void*  ei = d_in[1];
    const float* W1 = (const float*)d_in[2];
    const float* b1 = (const float*)d_in[3];
    const float* W2 = (const float*)d_in[4];
    const float* b2 = (const float*)d_in[5];
    const float* W3 = (const float*)d_in[6];
    const float* b3 = (const float*)d_in[7];
    float* out = (float*)d_out;

    _Float16* xh  = (_Float16*)((char*)d_ws + 256);          // 25.6 MB
    _Float16* W1f = xh + (size_t)N_NODES * 128;              // 64 KB

    k0_convert<<<2048, 256, 0, stream>>>(x, W1, xh, W1f);
    k2_edge_mlp<<<768, 256, 0, stream>>>(xh, ei, W1f, b1, W2, b2, W3, b3, out);
}